// Round 1
// baseline (424.817 us; speedup 1.0000x reference)
//
#include <hip/hip_runtime.h>

typedef __attribute__((ext_vector_type(8))) short short8;
typedef __attribute__((ext_vector_type(8))) __bf16 bf16x8;
typedef __attribute__((ext_vector_type(4))) float f32x4;

// sizes
#define B_ 4
#define C_ 64
#define H_ 128
#define W_ 128
#define P_ (H_*W_)      // 16384
#define E_ 16
#define Kk 3

// ws layout (bytes)
#define OFF_XT   0u
#define XT_BYTES (4u*130u*130u*64u*2u)          // 8,652,800
#define OFF_A    8652800u
#define A_BYTES  (1024u*576u*2u)                 // 1,179,648
#define OFF_R1   9832448u
#define R1_BYTES (4u*16u*16384u*4u)              // 4,194,304
#define OFF_PARA 14026752u

__device__ inline unsigned short f2bf(float f) {
    union { float f; unsigned u; } v; v.f = f;
    unsigned r = v.u + 0x7FFF + ((v.u >> 16) & 1);
    return (unsigned short)(r >> 16);
}

// ---------- zero xt (borders must be 0; simpler to zero all) ----------
__global__ __launch_bounds__(256) void k_zero(unsigned short* __restrict__ xt) {
    int i = blockIdx.x * 256 + threadIdx.x;
    if (i < (int)(XT_BYTES / 16)) {
        short8 z = {0,0,0,0,0,0,0,0};
        ((short8*)xt)[i] = z;
    }
}

// ---------- transpose+pad x (NCHW f32) -> xt[b][y+1][x+1][c] bf16 ----------
__global__ __launch_bounds__(128) void k_transpose(const float* __restrict__ x,
                                                   unsigned short* __restrict__ xt) {
    int b = blockIdx.x >> 7, y = blockIdx.x & 127;
    int t = threadIdx.x; // x coordinate
    const float* src = x + (size_t)b * C_ * P_ + y * W_ + t;
    unsigned short* dst = xt + ((size_t)(b * 130 + y + 1) * 130 + t + 1) * 64;
#pragma unroll
    for (int i = 0; i < 8; ++i) {
        short8 v;
#pragma unroll
        for (int j = 0; j < 8; ++j) v[j] = (short)f2bf(src[(size_t)(i * 8 + j) * P_]);
        ((short8*)dst)[i] = v;
    }
}

// ---------- build A[row=o*16+e][col=(kh*3+kw)*64+c] bf16 from W ----------
__global__ __launch_bounds__(256) void k_prepA(const float* __restrict__ Wsrc,
                                               unsigned short* __restrict__ A) {
    __shared__ float lw[9216];
    int o = blockIdx.x, t = threadIdx.x;
    const float* src = Wsrc + (size_t)o * 9216; // 576*16 per o, layout [j=c*9+tap][e]
    for (int lin = t; lin < 9216; lin += 256) lw[lin] = src[lin];
    __syncthreads();
    unsigned short* dst = A + (size_t)o * 16 * 576;
    for (int lin = t; lin < 9216; lin += 256) {
        int e = lin / 576, col = lin - e * 576;
        int tap = col >> 6, c = col & 63;
        dst[e * 576 + col] = f2bf(lw[(c * 9 + tap) * 16 + e]);
    }
}

// ---------- predictor conv1x1 + relu -> r1[b][e][p] f32 ----------
__global__ __launch_bounds__(256) void k_pred1(const float* __restrict__ x,
                                               const float* __restrict__ pw,
                                               const float* __restrict__ pb,
                                               float* __restrict__ r1) {
    __shared__ float lpw[1024];
    __shared__ float lpb[16];
    int t = threadIdx.x;
    for (int lin = t; lin < 1024; lin += 256) lpw[lin] = pw[lin];
    if (t < 16) lpb[t] = pb[t];
    __syncthreads();
    int gp = blockIdx.x * 256 + t;
    int b = gp >> 14, p = gp & 16383;
    const float* xs = x + (size_t)b * C_ * P_ + p;
    float s[16];
#pragma unroll
    for (int e = 0; e < 16; ++e) s[e] = lpb[e];
    for (int c = 0; c < 64; ++c) {
        float xv = xs[(size_t)c * P_];
#pragma unroll
        for (int e = 0; e < 16; ++e) s[e] = fmaf(lpw[e * 64 + c], xv, s[e]);
    }
    float* d = r1 + (size_t)b * 16 * P_ + p;
#pragma unroll
    for (int e = 0; e < 16; ++e) d[(size_t)e * P_] = fmaxf(s[e], 0.f);
}

// ---------- predictor conv3x3 -> para[b][e][p] f32 ----------
__global__ __launch_bounds__(256) void k_pred2(const float* __restrict__ r1,
                                               const float* __restrict__ cw,
                                               const float* __restrict__ cb,
                                               float* __restrict__ para) {
    __shared__ float lcw[2304];
    __shared__ float lcb[16];
    int t = threadIdx.x;
    for (int lin = t; lin < 2304; lin += 256) lcw[lin] = cw[lin];
    if (t < 16) lcb[t] = cb[t];
    __syncthreads();
    int gp = blockIdx.x * 256 + t;
    int b = gp >> 14, p = gp & 16383;
    int y = p >> 7, xc = p & 127;
    const float* rs = r1 + (size_t)b * 16 * P_;
    float s[16];
#pragma unroll
    for (int e = 0; e < 16; ++e) s[e] = lcb[e];
    for (int dy = 0; dy < 3; ++dy) {
        int yy = y + dy - 1;
        if (yy < 0 || yy > 127) continue;
        for (int dx = 0; dx < 3; ++dx) {
            int xv = xc + dx - 1;
            if (xv < 0 || xv > 127) continue;
            int q = yy * 128 + xv;
            int tap = dy * 3 + dx;
#pragma unroll
            for (int ep = 0; ep < 16; ++ep) {
                float v = rs[(size_t)ep * P_ + q];
#pragma unroll
                for (int e = 0; e < 16; ++e)
                    s[e] = fmaf(lcw[(e * 16 + ep) * 9 + tap], v, s[e]);
            }
        }
    }
    float* d = para + (size_t)b * 16 * P_ + p;
#pragma unroll
    for (int e = 0; e < 16; ++e) d[(size_t)e * P_] = s[e];
}

// ---------- main fused kernel ----------
// block = one image row (b,y), 128 pixels. 4 waves.
// M = 1024 rows (o*16+e), processed as 4 chunks of 256 rows; wave owns 4 o's/chunk.
// K = 576 ordered (kh,kw,c). B operand from LDS-staged 3 xt rows (XOR swizzled).
__global__ __launch_bounds__(256, 2) void k_main(const unsigned short* __restrict__ xt,
                                                 const unsigned short* __restrict__ A,
                                                 const float* __restrict__ para,
                                                 float* __restrict__ out) {
    __shared__ unsigned short lds[3 * 130 * 64]; // 49,920 B
    int b = blockIdx.x >> 7, y = blockIdx.x & 127;
    int tid = threadIdx.x;
    int wave = tid >> 6, lane = tid & 63, lhi = lane >> 4, llo = lane & 15;

    // stage 3 xt rows (y .. y+2 in padded coords), swizzle byte ^= ((xx&7)<<4)
    const unsigned short* xrow = xt + (size_t)(b * 130 + y) * 130 * 64;
    for (int ci = tid; ci < 3120; ci += 256) {
        int row = ci / 1040, rem = ci - row * 1040;
        int xx = rem >> 3, cc = rem & 7;
        short8 v = *(const short8*)(xrow + ((size_t)row * 130 + xx) * 64 + cc * 8);
        int lb = row * 16640 + xx * 128 + ((cc * 16) ^ ((xx & 7) << 4));
        *(short8*)((char*)lds + lb) = v;
    }
    __syncthreads();

    const float* pp = para + (size_t)b * 16 * P_ + y * 128;
    float* po = out + (size_t)b * 64 * P_ + y * 128;

    for (int chunk = 0; chunk < 4; ++chunk) {
        int obase = chunk * 16 + wave * 4;
        f32x4 acc[4][8];
#pragma unroll
        for (int f = 0; f < 4; ++f)
#pragma unroll
            for (int pg = 0; pg < 8; ++pg) acc[f][pg] = (f32x4){0.f, 0.f, 0.f, 0.f};

        const unsigned short* Ab = A + (size_t)(obase * 16 + llo) * 576 + lhi * 8;

        for (int ks = 0; ks < 18; ++ks) {
            int kh = ks / 6, r6 = ks - kh * 6;
            int kw = r6 >> 1;
            int cb = (ks & 1) * 64 + lhi * 16; // byte offset of c within 128B row
            bf16x8 af[4];
#pragma unroll
            for (int f = 0; f < 4; ++f)
                af[f] = *(const bf16x8*)(Ab + (size_t)f * 9216 + ks * 32);
            int sw = ((llo + kw) & 7) << 4;
            const char* bptr = (const char*)lds + kh * 16640 + (llo + kw) * 128 + (cb ^ sw);
            bf16x8 bf[8];
#pragma unroll
            for (int pg = 0; pg < 8; ++pg)
                bf[pg] = *(const bf16x8*)(bptr + pg * 2048);
#pragma unroll
            for (int f = 0; f < 4; ++f)
#pragma unroll
                for (int pg = 0; pg < 8; ++pg)
                    acc[f][pg] = __builtin_amdgcn_mfma_f32_16x16x32_bf16(af[f], bf[pg], acc[f][pg], 0, 0, 0);
        }

        // epilogue: multiply rows (e) by para[e,p], reduce over e
        float pv[8][4];
#pragma unroll
        for (int pg = 0; pg < 8; ++pg)
#pragma unroll
            for (int r = 0; r < 4; ++r)
                pv[pg][r] = pp[(size_t)(lhi * 4 + r) * P_ + pg * 16 + llo];

#pragma unroll
        for (int f = 0; f < 4; ++f) {
            int o = obase + f;
#pragma unroll
            for (int pg = 0; pg < 8; ++pg) {
                float s = acc[f][pg][0] * pv[pg][0] + acc[f][pg][1] * pv[pg][1] +
                          acc[f][pg][2] * pv[pg][2] + acc[f][pg][3] * pv[pg][3];
                s += __shfl_xor(s, 16);
                s += __shfl_xor(s, 32);
                if (lhi == 0) po[(size_t)o * P_ + pg * 16 + llo] = s;
            }
        }
    }
}

extern "C" void kernel_launch(void* const* d_in, const int* in_sizes, int n_in,
                              void* d_out, int out_size, void* d_ws, size_t ws_size,
                              hipStream_t stream) {
    const float* x  = (const float*)d_in[0];
    const float* W  = (const float*)d_in[1];
    const float* pw = (const float*)d_in[2];
    const float* pb = (const float*)d_in[3];
    const float* cw = (const float*)d_in[4];
    const float* cb = (const float*)d_in[5];
    float* out = (float*)d_out;
    char* ws = (char*)d_ws;
    unsigned short* xt = (unsigned short*)(ws + OFF_XT);
    unsigned short* Am = (unsigned short*)(ws + OFF_A);
    float* r1   = (float*)(ws + OFF_R1);
    float* para = (float*)(ws + OFF_PARA);

    hipLaunchKernelGGL(k_zero, dim3((XT_BYTES / 16 + 255) / 256), dim3(256), 0, stream, xt);
    hipLaunchKernelGGL(k_transpose, dim3(B_ * H_), dim3(128), 0, stream, x, xt);
    hipLaunchKernelGGL(k_prepA, dim3(64), dim3(256), 0, stream, W, Am);
    hipLaunchKernelGGL(k_pred1, dim3(B_ * P_ / 256), dim3(256), 0, stream, x, pw, pb, r1);
    hipLaunchKernelGGL(k_pred2, dim3(B_ * P_ / 256), dim3(256), 0, stream, r1, cw, cb, para);
    hipLaunchKernelGGL(k_main, dim3(B_ * H_), dim3(256), 0, stream, xt, Am, para, out);
}

// Round 2
// 141.143 us; speedup vs baseline: 3.0098x; 3.0098x over previous
//
#include <hip/hip_runtime.h>

typedef __attribute__((ext_vector_type(8))) short short8;
typedef __attribute__((ext_vector_type(8))) __bf16 bf16x8;
typedef __attribute__((ext_vector_type(4))) float f32x4;

// sizes
#define B_ 4
#define C_ 64
#define H_ 128
#define W_ 128
#define P_ (H_*W_)      // 16384
#define E_ 16
#define Kk 3

// ws layout (bytes)
#define OFF_XT   0u
#define XT_BYTES (4u*130u*130u*64u*2u)          // 8,652,800
#define OFF_A    8652800u
#define A_BYTES  (1024u*576u*2u)                 // 1,179,648
#define OFF_R1   9832448u
#define R1_BYTES (4u*16u*16384u*4u)              // 4,194,304
#define OFF_PARA 14026752u

__device__ inline unsigned short f2bf(float f) {
    union { float f; unsigned u; } v; v.f = f;
    unsigned r = v.u + 0x7FFF + ((v.u >> 16) & 1);
    return (unsigned short)(r >> 16);
}

// ---------- zero xt (borders must be 0; simpler to zero all) ----------
__global__ __launch_bounds__(256) void k_zero(unsigned short* __restrict__ xt) {
    int i = blockIdx.x * 256 + threadIdx.x;
    if (i < (int)(XT_BYTES / 16)) {
        short8 z = {0,0,0,0,0,0,0,0};
        ((short8*)xt)[i] = z;
    }
}

// ---------- transpose+pad x (NCHW f32) -> xt[b][y+1][x+1][c] bf16 ----------
__global__ __launch_bounds__(128) void k_transpose(const float* __restrict__ x,
                                                   unsigned short* __restrict__ xt) {
    int b = blockIdx.x >> 7, y = blockIdx.x & 127;
    int t = threadIdx.x; // x coordinate
    const float* src = x + (size_t)b * C_ * P_ + y * W_ + t;
    unsigned short* dst = xt + ((size_t)(b * 130 + y + 1) * 130 + t + 1) * 64;
#pragma unroll
    for (int i = 0; i < 8; ++i) {
        short8 v;
#pragma unroll
        for (int j = 0; j < 8; ++j) v[j] = (short)f2bf(src[(size_t)(i * 8 + j) * P_]);
        ((short8*)dst)[i] = v;
    }
}

// ---------- build A[row=o*16+e][col=(kh*3+kw)*64+c] bf16 from W ----------
__global__ __launch_bounds__(256) void k_prepA(const float* __restrict__ Wsrc,
                                               unsigned short* __restrict__ A) {
    __shared__ float lw[9216];
    int o = blockIdx.x, t = threadIdx.x;
    const float* src = Wsrc + (size_t)o * 9216; // 576*16 per o, layout [j=c*9+tap][e]
    for (int lin = t; lin < 9216; lin += 256) lw[lin] = src[lin];
    __syncthreads();
    unsigned short* dst = A + (size_t)o * 16 * 576;
    for (int lin = t; lin < 9216; lin += 256) {
        int e = lin / 576, col = lin - e * 576;
        int tap = col >> 6, c = col & 63;
        dst[e * 576 + col] = f2bf(lw[(c * 9 + tap) * 16 + e]);
    }
}

// ---------- predictor conv1x1 + relu -> r1[b][e][p] f32 ----------
__global__ __launch_bounds__(256) void k_pred1(const float* __restrict__ x,
                                               const float* __restrict__ pw,
                                               const float* __restrict__ pb,
                                               float* __restrict__ r1) {
    __shared__ float lpw[1024];
    __shared__ float lpb[16];
    int t = threadIdx.x;
    for (int lin = t; lin < 1024; lin += 256) lpw[lin] = pw[lin];
    if (t < 16) lpb[t] = pb[t];
    __syncthreads();
    int gp = blockIdx.x * 256 + t;
    int b = gp >> 14, p = gp & 16383;
    const float* xs = x + (size_t)b * C_ * P_ + p;
    float s[16];
#pragma unroll
    for (int e = 0; e < 16; ++e) s[e] = lpb[e];
    for (int c = 0; c < 64; ++c) {
        float xv = xs[(size_t)c * P_];
#pragma unroll
        for (int e = 0; e < 16; ++e) s[e] = fmaf(lpw[e * 64 + c], xv, s[e]);
    }
    float* d = r1 + (size_t)b * 16 * P_ + p;
#pragma unroll
    for (int e = 0; e < 16; ++e) d[(size_t)e * P_] = fmaxf(s[e], 0.f);
}

// ---------- predictor conv3x3 -> para[b][e][p] f32 ----------
__global__ __launch_bounds__(256) void k_pred2(const float* __restrict__ r1,
                                               const float* __restrict__ cw,
                                               const float* __restrict__ cb,
                                               float* __restrict__ para) {
    __shared__ float lcw[2304];
    __shared__ float lcb[16];
    int t = threadIdx.x;
    for (int lin = t; lin < 2304; lin += 256) lcw[lin] = cw[lin];
    if (t < 16) lcb[t] = cb[t];
    __syncthreads();
    int gp = blockIdx.x * 256 + t;
    int b = gp >> 14, p = gp & 16383;
    int y = p >> 7, xc = p & 127;
    const float* rs = r1 + (size_t)b * 16 * P_;
    float s[16];
#pragma unroll
    for (int e = 0; e < 16; ++e) s[e] = lcb[e];
    for (int dy = 0; dy < 3; ++dy) {
        int yy = y + dy - 1;
        if (yy < 0 || yy > 127) continue;
        for (int dx = 0; dx < 3; ++dx) {
            int xv = xc + dx - 1;
            if (xv < 0 || xv > 127) continue;
            int q = yy * 128 + xv;
            int tap = dy * 3 + dx;
#pragma unroll
            for (int ep = 0; ep < 16; ++ep) {
                float v = rs[(size_t)ep * P_ + q];
#pragma unroll
                for (int e = 0; e < 16; ++e)
                    s[e] = fmaf(lcw[(e * 16 + ep) * 9 + tap], v, s[e]);
            }
        }
    }
    float* d = para + (size_t)b * 16 * P_ + p;
#pragma unroll
    for (int e = 0; e < 16; ++e) d[(size_t)e * P_] = s[e];
}

// ---------- main fused kernel ----------
// block = 512 threads (8 waves), covers 4 image rows x 16 output channels.
// wave w: image row = w&3, o-half = w>>2 (8 o's via 2 chunks x 4 f).
// blockIdx decode pins pixel-groups to XCDs (byg ≡ xcd mod 8) so the whole A
// matrix (1.18 MB) stays L2-resident per XCD.
__global__ __launch_bounds__(512, 2) void k_main(const unsigned short* __restrict__ xt,
                                                 const unsigned short* __restrict__ A,
                                                 const float* __restrict__ para,
                                                 float* __restrict__ out) {
    __shared__ unsigned short lds[6 * 130 * 64]; // 99,840 B
    // decode: r = ((bygl*4 + osl) << 3) | xcd ; byg = bygl*8 + xcd
    int r = blockIdx.x;
    int xcd = r & 7;
    int ord = r >> 3;
    int osl = ord & 3;          // o-slice: 16 o's
    int bygl = ord >> 2;        // [0,16)
    int byg = bygl * 8 + xcd;   // [0,128)
    int b = byg >> 5, yg = byg & 31;
    int y0 = yg * 4;            // first image row of this block

    int tid = threadIdx.x;
    int wave = tid >> 6, lane = tid & 63, lhi = lane >> 4, llo = lane & 15;
    int wrow = wave & 3, ohalf = wave >> 2;

    // stage 6 padded xt rows (y0 .. y0+5), swizzle byte ^= ((xx&7)<<4)
    const unsigned short* xrow = xt + (size_t)(b * 130 + y0) * 130 * 64;
    for (int ci = tid; ci < 6240; ci += 512) {
        int row = ci / 1040, rem = ci - row * 1040;
        int xx = rem >> 3, cc = rem & 7;
        short8 v = *(const short8*)(xrow + ((size_t)row * 130 + xx) * 64 + cc * 8);
        int lb = row * 16640 + xx * 128 + ((cc * 16) ^ ((xx & 7) << 4));
        *(short8*)((char*)lds + lb) = v;
    }
    __syncthreads();

    int y = y0 + wrow;
    const float* pp = para + (size_t)b * 16 * P_ + y * 128;
    float* po = out + (size_t)b * 64 * P_ + y * 128;

    // chunk-invariant: para values for the epilogue reduction
    float pv[8][4];
#pragma unroll
    for (int pg = 0; pg < 8; ++pg)
#pragma unroll
        for (int rr = 0; rr < 4; ++rr)
            pv[pg][rr] = pp[(size_t)(lhi * 4 + rr) * P_ + pg * 16 + llo];

    for (int chunk = 0; chunk < 2; ++chunk) {
        int obase = osl * 16 + ohalf * 8 + chunk * 4;
        f32x4 acc[4][8];
#pragma unroll
        for (int f = 0; f < 4; ++f)
#pragma unroll
            for (int pg = 0; pg < 8; ++pg) acc[f][pg] = (f32x4){0.f, 0.f, 0.f, 0.f};

        const unsigned short* Ab = A + (size_t)(obase * 16 + llo) * 576 + lhi * 8;

        for (int ks = 0; ks < 18; ++ks) {
            int kh = ks / 6, r6 = ks - kh * 6;
            int kw = r6 >> 1;
            int cb = (ks & 1) * 64 + lhi * 16; // byte offset of c within 128B row
            bf16x8 af[4];
#pragma unroll
            for (int f = 0; f < 4; ++f)
                af[f] = *(const bf16x8*)(Ab + (size_t)f * 9216 + ks * 32);
            int sw = ((llo + kw) & 7) << 4;
            const char* bptr = (const char*)lds + (wrow + kh) * 16640 + (llo + kw) * 128 + (cb ^ sw);
            bf16x8 bf[8];
#pragma unroll
            for (int pg = 0; pg < 8; ++pg)
                bf[pg] = *(const bf16x8*)(bptr + pg * 2048);
#pragma unroll
            for (int f = 0; f < 4; ++f)
#pragma unroll
                for (int pg = 0; pg < 8; ++pg)
                    acc[f][pg] = __builtin_amdgcn_mfma_f32_16x16x32_bf16(af[f], bf[pg], acc[f][pg], 0, 0, 0);
        }

        // epilogue: multiply rows (e) by para[e,p], reduce over e
#pragma unroll
        for (int f = 0; f < 4; ++f) {
            int o = obase + f;
#pragma unroll
            for (int pg = 0; pg < 8; ++pg) {
                float s = acc[f][pg][0] * pv[pg][0] + acc[f][pg][1] * pv[pg][1] +
                          acc[f][pg][2] * pv[pg][2] + acc[f][pg][3] * pv[pg][3];
                s += __shfl_xor(s, 16);
                s += __shfl_xor(s, 32);
                if (lhi == 0)
                    __builtin_nontemporal_store(s, &po[(size_t)o * P_ + pg * 16 + llo]);
            }
        }
    }
}

extern "C" void kernel_launch(void* const* d_in, const int* in_sizes, int n_in,
                              void* d_out, int out_size, void* d_ws, size_t ws_size,
                              hipStream_t stream) {
    const float* x  = (const float*)d_in[0];
    const float* W  = (const float*)d_in[1];
    const float* pw = (const float*)d_in[2];
    const float* pb = (const float*)d_in[3];
    const float* cw = (const float*)d_in[4];
    const float* cb = (const float*)d_in[5];
    float* out = (float*)d_out;
    char* ws = (char*)d_ws;
    unsigned short* xt = (unsigned short*)(ws + OFF_XT);
    unsigned short* Am = (unsigned short*)(ws + OFF_A);
    float* r1   = (float*)(ws + OFF_R1);
    float* para = (float*)(ws + OFF_PARA);

    hipLaunchKernelGGL(k_zero, dim3((XT_BYTES / 16 + 255) / 256), dim3(256), 0, stream, xt);
    hipLaunchKernelGGL(k_transpose, dim3(B_ * H_), dim3(128), 0, stream, x, xt);
    hipLaunchKernelGGL(k_prepA, dim3(64), dim3(256), 0, stream, W, Am);
    hipLaunchKernelGGL(k_pred1, dim3(B_ * P_ / 256), dim3(256), 0, stream, x, pw, pb, r1);
    hipLaunchKernelGGL(k_pred2, dim3(B_ * P_ / 256), dim3(256), 0, stream, r1, cw, cb, para);
    hipLaunchKernelGGL(k_main, dim3(512), dim3(512), 0, stream, xt, Am, para, out);
}